// Round 4
// baseline (227.413 us; speedup 1.0000x reference)
//
#include <hip/hip_runtime.h>
#include <hip/hip_bf16.h>
#include <cstdint>
#include <cstddef>

// Problem constants (B,S,D,H = 2,2048,1024,16; DK=64)
#define BB 2
#define SS 2048
#define DD 1024
#define HH 16
#define DKK 64
#define MM (BB*SS)   // 4096 rows for the projection GEMMs

typedef __bf16 bf16x8 __attribute__((ext_vector_type(8)));
typedef float  f32x4  __attribute__((ext_vector_type(4)));

__device__ __forceinline__ unsigned short f2bf(float f) {
    unsigned u = __float_as_uint(f);
    u += 0x7FFF + ((u >> 16) & 1);   // round-to-nearest-even
    return (unsigned short)(u >> 16);
}

// packed f32x2 -> bf16x2 (gfx950 HW inst; 1 inst for 2 values)
#if __has_builtin(__builtin_amdgcn_cvt_pk_bf16_f32)
typedef __bf16 bf16v2 __attribute__((ext_vector_type(2)));
__device__ __forceinline__ unsigned pk_bf16(float a, float b) {
    bf16v2 v = __builtin_amdgcn_cvt_pk_bf16_f32(a, b);
    return __builtin_bit_cast(unsigned, v);
}
#else
__device__ __forceinline__ unsigned pk_bf16(float a, float b) {
    return (unsigned)f2bf(a) | ((unsigned)f2bf(b) << 16);
}
#endif

// async global->LDS, 16B per lane. LDS side must be wave-uniform base + lane*16.
__device__ __forceinline__ void gld_lds16(const void* g, void* l) {
    __builtin_amdgcn_global_load_lds(
        (const __attribute__((address_space(1))) unsigned int*)g,
        (__attribute__((address_space(3))) unsigned int*)l, 16, 0, 0);
}

// manual waitcnt: vmcnt=N, lgkmcnt=15 (no wait), expcnt=7 (no wait)
#define WAIT_VM4() __builtin_amdgcn_s_waitcnt(0x0F74)
#define WAIT_VM0() __builtin_amdgcn_s_waitcnt(0x0F70)
#define BARRIER()  __builtin_amdgcn_s_barrier()

// DPP 16-lane butterfly max (pure VALU, no LDS pipe)
#define DPP_F(x, ctrl) __int_as_float(__builtin_amdgcn_mov_dpp(__float_as_int(x), ctrl, 0xF, 0xF, true))
__device__ __forceinline__ float red_max16(float x) {
    x = fmaxf(x, DPP_F(x, 0xB1));    // quad_perm xor1
    x = fmaxf(x, DPP_F(x, 0x4E));    // quad_perm xor2
    x = fmaxf(x, DPP_F(x, 0x141));   // row_half_mirror
    x = fmaxf(x, DPP_F(x, 0x140));   // row_mirror
    return x;
}

// ---------------- RoPE tables: cos/sin[dk2][s], dk2=0..31, s=0..2047 ----------------
__global__ __launch_bounds__(256) void rope_tables(float* __restrict__ cosT,
                                                   float* __restrict__ sinT) {
    int i = blockIdx.x * 256 + threadIdx.x;   // 65536 total
    int dk2 = i >> 11, s = i & 2047;
    const float L2T_OVER_DK = 13.287712379549449f / 64.0f;  // log2(10000)/64
    float inv_freq = exp2f(-(float)(2 * dk2) * L2T_OVER_DK);
    float ang = (float)s * inv_freq;
    float sn, cs;
    __sincosf(ang, &sn, &cs);
    cosT[i] = cs;
    sinT[i] = sn;
}

// ---------------- fused fp32 -> bf16 cast (x + 4 weights, one launch) ----------------
__global__ __launch_bounds__(256) void cast_all(const float* __restrict__ x,
                                                const float* __restrict__ wq,
                                                const float* __restrict__ wk,
                                                const float* __restrict__ wv,
                                                const float* __restrict__ wo,
                                                unsigned short* __restrict__ xb,
                                                unsigned short* __restrict__ wb) {
    int i = (blockIdx.x * 256 + threadIdx.x) * 4;
    const float* src;
    unsigned short* dst;
    if (i < MM * DD) { src = x + i; dst = xb + i; }
    else {
        int e = i - MM * DD;
        int r = e >> 20;                    // 1M elements per weight
        const float* s0 = (r == 0) ? wq : (r == 1) ? wk : (r == 2) ? wv : wo;
        src = s0 + (e & ((1 << 20) - 1));
        dst = wb + e;
    }
    float4 v = *reinterpret_cast<const float4*>(src);
    ushort4 o;
    o.x = f2bf(v.x); o.y = f2bf(v.y); o.z = f2bf(v.z); o.w = f2bf(v.w);
    *reinterpret_cast<ushort4*>(dst) = o;
}

// ---------------- fused QKV GEMM: C[m,n] = sum_k A[m,k] * W[n,k], N=3072 ----------------
// region 0: Q + RoPE -> Qo [B,H,S,DK];  region 1: K + RoPE -> Ko;  region 2: V^T -> Vto [B,H,DK,S]
__global__ __launch_bounds__(256) void gemm_qkv(const unsigned short* __restrict__ A,
                                                const unsigned short* __restrict__ W,
                                                const float* __restrict__ cosT,
                                                const float* __restrict__ sinT,
                                                unsigned short* __restrict__ Qo,
                                                unsigned short* __restrict__ Ko,
                                                unsigned short* __restrict__ Vto) {
    __shared__ unsigned short As[128 * 32];
    __shared__ unsigned short Ws[128 * 32];
    const int tid  = threadIdx.x;
    const int wave = tid >> 6, lane = tid & 63;
    const int quad = lane >> 4, l16 = lane & 15;
    const int wm = wave >> 1, wn = wave & 1;
    const int m0 = blockIdx.y * 128, n0 = blockIdx.x * 128;
    const int sw3 = l16 & 3;

    f32x4 acc[4][4];
    for (int i = 0; i < 4; i++)
        for (int j = 0; j < 4; j++) acc[i][j] = f32x4{0.f, 0.f, 0.f, 0.f};

    for (int k0 = 0; k0 < DD; k0 += 32) {
        __syncthreads();
        for (int c = tid; c < 512; c += 256) {
            int row = c >> 2, g = c & 3;
            int gc = ((g ^ (row & 3)) << 3);
            gld_lds16(A + (size_t)(m0 + row) * DD + k0 + gc, As + c * 8);
            gld_lds16(W + (size_t)(n0 + row) * DD + k0 + gc, Ws + c * 8);
        }
        __syncthreads();
        bf16x8 af[4], bfb[4];
        for (int i = 0; i < 4; i++)
            af[i] = *reinterpret_cast<const bf16x8*>(As + (wm * 64 + i * 16 + l16) * 32 + ((quad ^ sw3) << 3));
        for (int j = 0; j < 4; j++)
            bfb[j] = *reinterpret_cast<const bf16x8*>(Ws + (wn * 64 + j * 16 + l16) * 32 + ((quad ^ sw3) << 3));
        for (int i = 0; i < 4; i++)
            for (int j = 0; j < 4; j++)
                acc[i][j] = __builtin_amdgcn_mfma_f32_16x16x32_bf16(af[i], bfb[j], acc[i][j], 0, 0, 0);
    }

    const int region = n0 >> 10;
    if (region < 2) {
        unsigned short* Co = region ? Ko : Qo;
        for (int i = 0; i < 4; i++) {
            int mrow = m0 + wm * 64 + i * 16 + quad * 4;
            int b = mrow >> 11, s0 = mrow & 2047;
            for (int j = 0; j < 4; j++) {
                int nc = (n0 + wn * 64 + j * 16 + l16) & 1023;
                int h = nc >> 6, dk = nc & 63;
                const float4 cs4 = *reinterpret_cast<const float4*>(cosT + (dk >> 1) * 2048 + s0);
                const float4 sn4 = *reinterpret_cast<const float4*>(sinT + (dk >> 1) * 2048 + s0);
                float css[4] = {cs4.x, cs4.y, cs4.z, cs4.w};
                float sns[4] = {sn4.x, sn4.y, sn4.z, sn4.w};
                for (int r = 0; r < 4; r++) {
                    float v = acc[i][j][r];
                    float partner = __shfl_xor(v, 1, 64);  // lane^1 holds dk^1 (RoPE pair)
                    float outv = v * css[r] + ((dk & 1) ? partner : -partner) * sns[r];
                    Co[((size_t)(b * HH + h) * SS + (s0 + r)) * DKK + dk] = f2bf(outv);
                }
            }
        }
    } else {
        // V: write transposed Vt[b][h][dk][s]
        __syncthreads();                       // other waves done reading As
        unsigned short* T = As + wave * 1024;  // per-wave 16x16 scratch, stride 17
        const int dkl = lane >> 2, s4 = (lane & 3) * 4;
        for (int i = 0; i < 4; i++) {
            int ms0 = m0 + wm * 64 + i * 16;
            for (int j = 0; j < 4; j++) {
                int nc0 = n0 + wn * 64 + j * 16;
                for (int r = 0; r < 4; r++)
                    T[(quad * 4 + r) * 17 + l16] = f2bf(acc[i][j][r]);
                // same-wave LDS RAW: compiler orders via lgkmcnt
                ushort4 o;
                o.x = T[(s4 + 0) * 17 + dkl];
                o.y = T[(s4 + 1) * 17 + dkl];
                o.z = T[(s4 + 2) * 17 + dkl];
                o.w = T[(s4 + 3) * 17 + dkl];
                int nc = (nc0 + dkl) & 1023;
                int h = nc >> 6, dk = nc & 63;
                int m = ms0 + s4;
                int b = m >> 11, s = m & 2047;
                *reinterpret_cast<ushort4*>(Vto + ((size_t)((b * HH + h) * DKK + dk)) * SS + s) = o;
            }
        }
    }
}

// ---------------- out-projection GEMM: 64x128 tile (grid 512 = 2 blocks/CU) ----------------
__global__ __launch_bounds__(256) void gemm_out(const unsigned short* __restrict__ A,
                                                const unsigned short* __restrict__ W,
                                                float* __restrict__ C) {
    __shared__ unsigned short As[64 * 32];
    __shared__ unsigned short Ws[128 * 32];
    const int tid  = threadIdx.x;
    const int wave = tid >> 6, lane = tid & 63;
    const int quad = lane >> 4, l16 = lane & 15;
    const int wm = wave >> 1, wn = wave & 1;
    const int m0 = blockIdx.y * 64, n0 = blockIdx.x * 128;
    const int sw3 = l16 & 3;

    f32x4 acc[2][4];
    for (int i = 0; i < 2; i++)
        for (int j = 0; j < 4; j++) acc[i][j] = f32x4{0.f, 0.f, 0.f, 0.f};

    for (int k0 = 0; k0 < DD; k0 += 32) {
        __syncthreads();
        {
            int row = tid >> 2, g = tid & 3;
            int gc = ((g ^ (row & 3)) << 3);
            gld_lds16(A + (size_t)(m0 + row) * DD + k0 + gc, As + tid * 8);
        }
        for (int c = tid; c < 512; c += 256) {
            int row = c >> 2, g = c & 3;
            int gc = ((g ^ (row & 3)) << 3);
            gld_lds16(W + (size_t)(n0 + row) * DD + k0 + gc, Ws + c * 8);
        }
        __syncthreads();
        bf16x8 af[2], bfb[4];
        for (int i = 0; i < 2; i++)
            af[i] = *reinterpret_cast<const bf16x8*>(As + (wm * 32 + i * 16 + l16) * 32 + ((quad ^ sw3) << 3));
        for (int j = 0; j < 4; j++)
            bfb[j] = *reinterpret_cast<const bf16x8*>(Ws + (wn * 64 + j * 16 + l16) * 32 + ((quad ^ sw3) << 3));
        for (int i = 0; i < 2; i++)
            for (int j = 0; j < 4; j++)
                acc[i][j] = __builtin_amdgcn_mfma_f32_16x16x32_bf16(af[i], bfb[j], acc[i][j], 0, 0, 0);
    }

    for (int i = 0; i < 2; i++) {
        int mrow = m0 + wm * 32 + i * 16 + quad * 4;
        for (int j = 0; j < 4; j++) {
            int ncol = n0 + wn * 64 + j * 16 + l16;
            for (int r = 0; r < 4; r++)
                C[(size_t)(mrow + r) * DD + ncol] = acc[i][j][r];
        }
    }
}

// ---------------- Flash attention: paired q-tiles + async ping-pong prefetch ----------------
// Block t handles q-tiles t (lo) and 31-t (hi): every block = exactly 33 tile-units.
// l accumulated via MFMA ones-column (no cross-lane sum); P via packed bf16 cvt.
__global__ __launch_bounds__(256) void attn_kernel(const unsigned short* __restrict__ Qb,
                                                   const unsigned short* __restrict__ Kb,
                                                   const unsigned short* __restrict__ Vtb,
                                                   unsigned short* __restrict__ attn) {
    __shared__ unsigned short K0s[64 * 64], V0s[64 * 64];   // ping
    __shared__ unsigned short K1s[64 * 64], V1s[64 * 64];   // pong
    __shared__ unsigned short Ps[4][16 * 72];               // per-wave P round-trip

    const int tid  = threadIdx.x;
    const int wave = tid >> 6, lane = tid & 63;
    const int quad = lane >> 4, l16 = lane & 15;
    const int t  = blockIdx.x;            // 0..15 (heaviest first)
    const int bh = blockIdx.y;
    const int sw = l16 & 7;
    const int qlo = t * 64, qhi = (31 - t) * 64;
    const int nIter = 32 - t;

    const unsigned short* Qg = Qb  + (size_t)bh * SS * DKK;
    const unsigned short* Kg = Kb  + (size_t)bh * SS * DKK;
    const unsigned short* Vg = Vtb + (size_t)bh * DKK * SS;  // [dk][s]

    bf16x8 qL0 = *reinterpret_cast<const bf16x8*>(Qg + (size_t)(qlo + wave * 16 + l16) * DKK + quad * 8);
    bf16x8 qL1 = *reinterpret_cast<const bf16x8*>(Qg + (size_t)(qlo + wave * 16 + l16) * DKK + 32 + quad * 8);
    bf16x8 qH0 = *reinterpret_cast<const bf16x8*>(Qg + (size_t)(qhi + wave * 16 + l16) * DKK + quad * 8);
    bf16x8 qH1 = *reinterpret_cast<const bf16x8*>(Qg + (size_t)(qhi + wave * 16 + l16) * DKK + 32 + quad * 8);

    bf16x8 vone;
    for (int tt = 0; tt < 8; tt++) vone[tt] = (__bf16)1.0f;

    f32x4 aoL[4], aoH[4], alL, alH;   // al*: ones-column accumulator = row sums of P
    float mL[4], mH[4];
    for (int j = 0; j < 4; j++) { aoL[j] = f32x4{0.f,0.f,0.f,0.f}; aoH[j] = f32x4{0.f,0.f,0.f,0.f}; }
    alL = f32x4{0.f,0.f,0.f,0.f}; alH = f32x4{0.f,0.f,0.f,0.f};
    for (int r = 0; r < 4; r++) { mL[r] = mH[r] = -1e30f; }

    auto stage = [&](int it, unsigned short* Kd, unsigned short* Vd) {
        const int kv0 = it * 64;
        for (int c = tid; c < 512; c += 256) {
            int row = c >> 3, g = c & 7;
            int gc = ((g ^ (row & 7)) << 3);
            gld_lds16(Kg + (size_t)(kv0 + row) * DKK + gc, Kd + c * 8);
            gld_lds16(Vg + (size_t)row * SS + kv0 + gc, Vd + c * 8);
        }
    };

    const float C1 = 0.18033688011112042f;  // log2(e) / sqrt(DK)=8

    auto do_tile = [&](const unsigned short* Kd, const unsigned short* Vd,
                       bf16x8 q0f, bf16x8 q1f, bool diag,
                       f32x4* ao, f32x4& al, float* mr) {
        f32x4 sc[4];
        for (int j = 0; j < 4; j++) {
            const unsigned short* kr = Kd + (j * 16 + l16) * 64;
            bf16x8 kf0 = *reinterpret_cast<const bf16x8*>(kr + ((quad ^ sw) << 3));
            bf16x8 kf1 = *reinterpret_cast<const bf16x8*>(kr + (((4 + quad) ^ sw) << 3));
            f32x4 s = f32x4{0.f, 0.f, 0.f, 0.f};
            s = __builtin_amdgcn_mfma_f32_16x16x32_bf16(q0f, kf0, s, 0, 0, 0);
            s = __builtin_amdgcn_mfma_f32_16x16x32_bf16(q1f, kf1, s, 0, 0, 0);
            sc[j] = s;
        }
        if (diag) {
            for (int j = 0; j < 4; j++) {
                int lcol = j * 16 + l16;
                for (int r = 0; r < 4; r++) {
                    int lrow = wave * 16 + quad * 4 + r;
                    if (lcol > lrow) sc[j][r] = -1e30f;
                }
            }
        }
        float ar[4];
        for (int r = 0; r < 4; r++) {
            float mx = red_max16(fmaxf(fmaxf(sc[0][r], sc[1][r]), fmaxf(sc[2][r], sc[3][r])));
            float mnew = fmaxf(mr[r], mx);
            ar[r] = exp2f((mr[r] - mnew) * C1);
            float nb = -mnew * C1;
            for (int j = 0; j < 4; j++)
                sc[j][r] = exp2f(fmaf(sc[j][r], C1, nb));
            mr[r] = mnew;
        }
        for (int j = 0; j < 4; j++)
            for (int r = 0; r < 4; r++) ao[j][r] *= ar[r];
        for (int r = 0; r < 4; r++) al[r] *= ar[r];

        // P: C-layout -> per-wave LDS (packed cvt) -> A-layout (same-wave RAW, lgkm-ordered)
        unsigned short* Pw = Ps[wave];
        for (int r = 0; r < 4; r++) {
            unsigned pA = pk_bf16(sc[0][r], sc[1][r]);
            unsigned pB = pk_bf16(sc[2][r], sc[3][r]);
            int ro = (quad * 4 + r) * 72;
            Pw[ro + l16]      = (unsigned short)pA;
            Pw[ro + 16 + l16] = (unsigned short)(pA >> 16);
            Pw[ro + 32 + l16] = (unsigned short)pB;
            Pw[ro + 48 + l16] = (unsigned short)(pB >> 16);
        }

        for (int ko = 0; ko < 64; ko += 32) {
            bf16x8 pf = *reinterpret_cast<const bf16x8*>(Pw + l16 * 72 + ko + quad * 8);
            al = __builtin_amdgcn_mfma_f32_16x16x32_bf16(pf, vone, al, 0, 0, 0);
            int gh = (ko >> 3) + quad;
            for (int j = 0; j < 4; j++) {
                bf16x8 vf = *reinterpret_cast<const bf16x8*>(Vd + (j * 16 + l16) * 64 + ((gh ^ sw) << 3));
                ao[j] = __builtin_amdgcn_mfma_f32_16x16x32_bf16(pf, vf, ao[j], 0, 0, 0);
            }
        }
    };

    // ping-pong K-loop: raw barriers + vmcnt(4); next tile's LDS-DMA stays in flight.
    stage(0, K0s, V0s);
    int it = 0;
    while (true) {
        BARRIER();
        if (it + 1 < nIter) { stage(it + 1, K1s, V1s); WAIT_VM4(); } else WAIT_VM0();
        BARRIER();
        do_tile(K0s, V0s, qH0, qH1, it == nIter - 1, aoH, alH, mH);
        if (it <= t) do_tile(K0s, V0s, qL0, qL1, it == t, aoL, alL, mL);
        if (++it >= nIter) break;

        BARRIER();
        if (it + 1 < nIter) { stage(it + 1, K0s, V0s); WAIT_VM4(); } else WAIT_VM0();
        BARRIER();
        do_tile(K1s, V1s, qH0, qH1, it == nIter - 1, aoH, alH, mH);
        if (it <= t) do_tile(K1s, V1s, qL0, qL1, it == t, aoL, alL, mL);
        if (++it >= nIter) break;
    }

    const int b = bh >> 4, h = bh & 15;
    for (int r = 0; r < 4; r++) {
        float invL = __builtin_amdgcn_rcpf(alL[r]);
        float invH = __builtin_amdgcn_rcpf(alH[r]);
        int srL = qlo + wave * 16 + quad * 4 + r;
        int srH = qhi + wave * 16 + quad * 4 + r;
        for (int j = 0; j < 4; j++) {
            attn[((size_t)(b * SS + srL)) * DD + h * DKK + j * 16 + l16] = f2bf(aoL[j][r] * invL);
            attn[((size_t)(b * SS + srH)) * DD + h * DKK + j * 16 + l16] = f2bf(aoH[j][r] * invH);
        }
    }
}

// ---------------- launch ----------------
extern "C" void kernel_launch(void* const* d_in, const int* in_sizes, int n_in,
                              void* d_out, int out_size, void* d_ws, size_t ws_size,
                              hipStream_t stream) {
    const float* x  = (const float*)d_in[0];
    const float* Wq = (const float*)d_in[1];
    const float* Wk = (const float*)d_in[2];
    const float* Wv = (const float*)d_in[3];
    const float* Wo = (const float*)d_in[4];

    char* ws = (char*)d_ws;
    const size_t MB = 1u << 20;
    unsigned short* xb    = (unsigned short*)(ws);             // 8 MB; reused as attnb later
    unsigned short* wb    = (unsigned short*)(ws + 8  * MB);   // 8 MB  [Wq|Wk|Wv|Wo] bf16
    unsigned short* Qbuf  = (unsigned short*)(ws + 16 * MB);   // 8 MB [B,H,S,DK]
    unsigned short* Kbuf  = (unsigned short*)(ws + 24 * MB);   // 8 MB [B,H,S,DK]
    unsigned short* Vtbuf = (unsigned short*)(ws + 32 * MB);   // 8 MB [B,H,DK,S]
    float* cosT = (float*)(ws + 40 * MB);                      // 256 KB [32][2048]
    float* sinT = (float*)(ws + 40 * MB + (256u << 10));       // 256 KB
    unsigned short* attnb = xb;   // xb is dead after gemm_qkv; alias saves 8 MB

    rope_tables<<<256, 256, 0, stream>>>(cosT, sinT);
    cast_all<<<8192, 256, 0, stream>>>(x, Wq, Wk, Wv, Wo, xb, wb);

    // fused QKV projection: N=3072 packed, grid 768 blocks = 3/CU
    gemm_qkv<<<dim3(24, 32), 256, 0, stream>>>(xb, wb, cosT, sinT, Qbuf, Kbuf, Vtbuf);

    // paired-tile flash attention: grid 512 blocks, uniform 33 tile-units each
    attn_kernel<<<dim3(16, BB * HH), 256, 0, stream>>>(Qbuf, Kbuf, Vtbuf, attnb);

    // out-projection: 64x128 tile, grid 512 = 2/CU, fp32 epilogue
    gemm_out<<<dim3(8, 64), 256, 0, stream>>>(attnb, wb + 3 * 1024 * 1024, (float*)d_out);
}

// Round 5
// 225.888 us; speedup vs baseline: 1.0068x; 1.0068x over previous
//
#include <hip/hip_runtime.h>
#include <hip/hip_bf16.h>
#include <cstdint>
#include <cstddef>

// Problem constants (B,S,D,H = 2,2048,1024,16; DK=64)
#define BB 2
#define SS 2048
#define DD 1024
#define HH 16
#define DKK 64
#define MM (BB*SS)   // 4096 rows for the projection GEMMs

typedef __bf16 bf16x8 __attribute__((ext_vector_type(8)));
typedef float  f32x4  __attribute__((ext_vector_type(4)));

__device__ __forceinline__ unsigned short f2bf(float f) {
    unsigned u = __float_as_uint(f);
    u += 0x7FFF + ((u >> 16) & 1);   // round-to-nearest-even
    return (unsigned short)(u >> 16);
}

// packed f32x2 -> bf16x2 (gfx950 HW inst; 1 inst for 2 values)
#if __has_builtin(__builtin_amdgcn_cvt_pk_bf16_f32)
typedef __bf16 bf16v2 __attribute__((ext_vector_type(2)));
__device__ __forceinline__ unsigned pk_bf16(float a, float b) {
    bf16v2 v = __builtin_amdgcn_cvt_pk_bf16_f32(a, b);
    return __builtin_bit_cast(unsigned, v);
}
#else
__device__ __forceinline__ unsigned pk_bf16(float a, float b) {
    return (unsigned)f2bf(a) | ((unsigned)f2bf(b) << 16);
}
#endif

// async global->LDS, 16B per lane. LDS side must be wave-uniform base + lane*16.
__device__ __forceinline__ void gld_lds16(const void* g, void* l) {
    __builtin_amdgcn_global_load_lds(
        (const __attribute__((address_space(1))) unsigned int*)g,
        (__attribute__((address_space(3))) unsigned int*)l, 16, 0, 0);
}

// manual waitcnt: vmcnt=N, lgkmcnt=15 (no wait), expcnt=7 (no wait)
#define WAIT_VM4() __builtin_amdgcn_s_waitcnt(0x0F74)
#define WAIT_VM0() __builtin_amdgcn_s_waitcnt(0x0F70)
#define BARRIER()  __builtin_amdgcn_s_barrier()

// DPP 16-lane butterfly max (pure VALU, no LDS pipe)
#define DPP_F(x, ctrl) __int_as_float(__builtin_amdgcn_mov_dpp(__float_as_int(x), ctrl, 0xF, 0xF, true))
__device__ __forceinline__ float red_max16(float x) {
    x = fmaxf(x, DPP_F(x, 0xB1));    // quad_perm xor1
    x = fmaxf(x, DPP_F(x, 0x4E));    // quad_perm xor2
    x = fmaxf(x, DPP_F(x, 0x141));   // row_half_mirror
    x = fmaxf(x, DPP_F(x, 0x140));   // row_mirror
    return x;
}

// ---------------- fused fp32 -> bf16 cast (x + 4 weights, one launch) ----------------
__global__ __launch_bounds__(256) void cast_all(const float* __restrict__ x,
                                                const float* __restrict__ wq,
                                                const float* __restrict__ wk,
                                                const float* __restrict__ wv,
                                                const float* __restrict__ wo,
                                                unsigned short* __restrict__ xb,
                                                unsigned short* __restrict__ wb) {
    int i = (blockIdx.x * 256 + threadIdx.x) * 4;
    const float* src;
    unsigned short* dst;
    if (i < MM * DD) { src = x + i; dst = xb + i; }
    else {
        int e = i - MM * DD;
        int r = e >> 20;                    // 1M elements per weight
        const float* s0 = (r == 0) ? wq : (r == 1) ? wk : (r == 2) ? wv : wo;
        src = s0 + (e & ((1 << 20) - 1));
        dst = wb + e;
    }
    float4 v = *reinterpret_cast<const float4*>(src);
    ushort4 o;
    o.x = f2bf(v.x); o.y = f2bf(v.y); o.z = f2bf(v.z); o.w = f2bf(v.w);
    *reinterpret_cast<ushort4*>(dst) = o;
}

// ---------------- fused QKV GEMM: C[m,n] = sum_k A[m,k] * W[n,k], N=3072 ----------------
// region 0: Q + RoPE -> Qo [B,H,S,DK];  region 1: K + RoPE -> Ko;  region 2: V^T -> Vto [B,H,DK,S]
// Q/K epilogue: fp32 LDS transpose so each lane owns 4 consecutive dk at one s ->
// in-lane RoPE pairs (no shfl), 2 sincos per (i,j) instead of 4, one 8B store.
__global__ __launch_bounds__(256) void gemm_qkv(const unsigned short* __restrict__ A,
                                                const unsigned short* __restrict__ W,
                                                unsigned short* __restrict__ Qo,
                                                unsigned short* __restrict__ Ko,
                                                unsigned short* __restrict__ Vto) {
    __shared__ __align__(16) unsigned short As[128 * 32];
    __shared__ __align__(16) unsigned short Ws[128 * 32];
    const int tid  = threadIdx.x;
    const int wave = tid >> 6, lane = tid & 63;
    const int quad = lane >> 4, l16 = lane & 15;
    const int wm = wave >> 1, wn = wave & 1;
    const int m0 = blockIdx.y * 128, n0 = blockIdx.x * 128;
    const int sw3 = l16 & 3;

    f32x4 acc[4][4];
    for (int i = 0; i < 4; i++)
        for (int j = 0; j < 4; j++) acc[i][j] = f32x4{0.f, 0.f, 0.f, 0.f};

    for (int k0 = 0; k0 < DD; k0 += 32) {
        __syncthreads();
        for (int c = tid; c < 512; c += 256) {
            int row = c >> 2, g = c & 3;
            int gc = ((g ^ (row & 3)) << 3);
            gld_lds16(A + (size_t)(m0 + row) * DD + k0 + gc, As + c * 8);
            gld_lds16(W + (size_t)(n0 + row) * DD + k0 + gc, Ws + c * 8);
        }
        __syncthreads();
        bf16x8 af[4], bfb[4];
        for (int i = 0; i < 4; i++)
            af[i] = *reinterpret_cast<const bf16x8*>(As + (wm * 64 + i * 16 + l16) * 32 + ((quad ^ sw3) << 3));
        for (int j = 0; j < 4; j++)
            bfb[j] = *reinterpret_cast<const bf16x8*>(Ws + (wn * 64 + j * 16 + l16) * 32 + ((quad ^ sw3) << 3));
        for (int i = 0; i < 4; i++)
            for (int j = 0; j < 4; j++)
                acc[i][j] = __builtin_amdgcn_mfma_f32_16x16x32_bf16(af[i], bfb[j], acc[i][j], 0, 0, 0);
    }

    const int region = n0 >> 10;
    const float L2T_OVER_DK = 13.287712379549449f / 64.0f;  // log2(10000)/64
    if (region < 2) {
        __syncthreads();                           // other waves done reading As
        float* T = (float*)As + wave * 512;        // per-wave 512-float scratch, stride 20
        unsigned short* Co = region ? Ko : Qo;
        const int sl  = lane >> 2;                 // 0..15 local s
        const int dkl = (lane & 3) * 4;            // 0,4,8,12
        for (int i = 0; i < 4; i++) {
            int ms0 = m0 + wm * 64 + i * 16;
            int b = ms0 >> 11;
            int s = (ms0 & 2047) + sl;
            for (int j = 0; j < 4; j++) {
                int nc = (n0 + wn * 64 + j * 16) & 1023;  // 16-aligned
                int h = nc >> 6;
                int dk0 = (nc & 63) + dkl;                // even, 8B-aligned group
                for (int r = 0; r < 4; r++)
                    T[(quad * 4 + r) * 20 + l16] = acc[i][j][r];
                // same-wave LDS RAW: in-order DS pipe + compiler lgkmcnt
                float4 v4 = *reinterpret_cast<const float4*>(T + sl * 20 + dkl);
                float if0 = exp2f(-(float)(dk0)     * L2T_OVER_DK);
                float if1 = exp2f(-(float)(dk0 + 2) * L2T_OVER_DK);
                float sn0, cs0, sn1, cs1;
                __sincosf((float)s * if0, &sn0, &cs0);
                __sincosf((float)s * if1, &sn1, &cs1);
                float e0 = v4.x * cs0 - v4.y * sn0;
                float o0 = v4.y * cs0 + v4.x * sn0;
                float e1 = v4.z * cs1 - v4.w * sn1;
                float o1 = v4.w * cs1 + v4.z * sn1;
                uint2 st;
                st.x = pk_bf16(e0, o0);
                st.y = pk_bf16(e1, o1);
                *reinterpret_cast<uint2*>(Co + ((size_t)(b * HH + h) * SS + s) * DKK + dk0) = st;
            }
        }
    } else {
        // V: write transposed Vt[b][h][dk][s]
        __syncthreads();                       // other waves done reading As
        unsigned short* T = As + wave * 1024;  // per-wave 16x16 scratch, stride 17
        const int dkl = lane >> 2, s4 = (lane & 3) * 4;
        for (int i = 0; i < 4; i++) {
            int ms0 = m0 + wm * 64 + i * 16;
            for (int j = 0; j < 4; j++) {
                int nc0 = n0 + wn * 64 + j * 16;
                for (int r = 0; r < 4; r++)
                    T[(quad * 4 + r) * 17 + l16] = f2bf(acc[i][j][r]);
                // same-wave LDS RAW: compiler orders via lgkmcnt
                ushort4 o;
                o.x = T[(s4 + 0) * 17 + dkl];
                o.y = T[(s4 + 1) * 17 + dkl];
                o.z = T[(s4 + 2) * 17 + dkl];
                o.w = T[(s4 + 3) * 17 + dkl];
                int nc = (nc0 + dkl) & 1023;
                int h = nc >> 6, dk = nc & 63;
                int m = ms0 + s4;
                int b = m >> 11, s = m & 2047;
                *reinterpret_cast<ushort4*>(Vto + ((size_t)((b * HH + h) * DKK + dk)) * SS + s) = o;
            }
        }
    }
}

// ---------------- out-projection GEMM: 64x128 tile (grid 512 = 2 blocks/CU) ----------------
__global__ __launch_bounds__(256) void gemm_out(const unsigned short* __restrict__ A,
                                                const unsigned short* __restrict__ W,
                                                float* __restrict__ C) {
    __shared__ unsigned short As[64 * 32];
    __shared__ unsigned short Ws[128 * 32];
    const int tid  = threadIdx.x;
    const int wave = tid >> 6, lane = tid & 63;
    const int quad = lane >> 4, l16 = lane & 15;
    const int wm = wave >> 1, wn = wave & 1;
    const int m0 = blockIdx.y * 64, n0 = blockIdx.x * 128;
    const int sw3 = l16 & 3;

    f32x4 acc[2][4];
    for (int i = 0; i < 2; i++)
        for (int j = 0; j < 4; j++) acc[i][j] = f32x4{0.f, 0.f, 0.f, 0.f};

    for (int k0 = 0; k0 < DD; k0 += 32) {
        __syncthreads();
        {
            int row = tid >> 2, g = tid & 3;
            int gc = ((g ^ (row & 3)) << 3);
            gld_lds16(A + (size_t)(m0 + row) * DD + k0 + gc, As + tid * 8);
        }
        for (int c = tid; c < 512; c += 256) {
            int row = c >> 2, g = c & 3;
            int gc = ((g ^ (row & 3)) << 3);
            gld_lds16(W + (size_t)(n0 + row) * DD + k0 + gc, Ws + c * 8);
        }
        __syncthreads();
        bf16x8 af[2], bfb[4];
        for (int i = 0; i < 2; i++)
            af[i] = *reinterpret_cast<const bf16x8*>(As + (wm * 32 + i * 16 + l16) * 32 + ((quad ^ sw3) << 3));
        for (int j = 0; j < 4; j++)
            bfb[j] = *reinterpret_cast<const bf16x8*>(Ws + (wn * 64 + j * 16 + l16) * 32 + ((quad ^ sw3) << 3));
        for (int i = 0; i < 2; i++)
            for (int j = 0; j < 4; j++)
                acc[i][j] = __builtin_amdgcn_mfma_f32_16x16x32_bf16(af[i], bfb[j], acc[i][j], 0, 0, 0);
    }

    for (int i = 0; i < 2; i++) {
        int mrow = m0 + wm * 32 + i * 16 + quad * 4;
        for (int j = 0; j < 4; j++) {
            int ncol = n0 + wn * 64 + j * 16 + l16;
            for (int r = 0; r < 4; r++)
                C[(size_t)(mrow + r) * DD + ncol] = acc[i][j][r];
        }
    }
}

// ---------------- Flash attention: paired q-tiles + async ping-pong prefetch ----------------
// Block t handles q-tiles t (lo) and 31-t (hi): every block = exactly 33 tile-units.
// l accumulated via MFMA ones-column (no cross-lane sum); P via packed bf16 cvt.
__global__ __launch_bounds__(256) void attn_kernel(const unsigned short* __restrict__ Qb,
                                                   const unsigned short* __restrict__ Kb,
                                                   const unsigned short* __restrict__ Vtb,
                                                   unsigned short* __restrict__ attn) {
    __shared__ unsigned short K0s[64 * 64], V0s[64 * 64];   // ping
    __shared__ unsigned short K1s[64 * 64], V1s[64 * 64];   // pong
    __shared__ unsigned short Ps[4][16 * 72];               // per-wave P round-trip

    const int tid  = threadIdx.x;
    const int wave = tid >> 6, lane = tid & 63;
    const int quad = lane >> 4, l16 = lane & 15;
    const int t  = blockIdx.x;            // 0..15 (heaviest first)
    const int bh = blockIdx.y;
    const int sw = l16 & 7;
    const int qlo = t * 64, qhi = (31 - t) * 64;
    const int nIter = 32 - t;

    const unsigned short* Qg = Qb  + (size_t)bh * SS * DKK;
    const unsigned short* Kg = Kb  + (size_t)bh * SS * DKK;
    const unsigned short* Vg = Vtb + (size_t)bh * DKK * SS;  // [dk][s]

    bf16x8 qL0 = *reinterpret_cast<const bf16x8*>(Qg + (size_t)(qlo + wave * 16 + l16) * DKK + quad * 8);
    bf16x8 qL1 = *reinterpret_cast<const bf16x8*>(Qg + (size_t)(qlo + wave * 16 + l16) * DKK + 32 + quad * 8);
    bf16x8 qH0 = *reinterpret_cast<const bf16x8*>(Qg + (size_t)(qhi + wave * 16 + l16) * DKK + quad * 8);
    bf16x8 qH1 = *reinterpret_cast<const bf16x8*>(Qg + (size_t)(qhi + wave * 16 + l16) * DKK + 32 + quad * 8);

    bf16x8 vone;
    for (int tt = 0; tt < 8; tt++) vone[tt] = (__bf16)1.0f;

    f32x4 aoL[4], aoH[4], alL, alH;   // al*: ones-column accumulator = row sums of P
    float mL[4], mH[4];
    for (int j = 0; j < 4; j++) { aoL[j] = f32x4{0.f,0.f,0.f,0.f}; aoH[j] = f32x4{0.f,0.f,0.f,0.f}; }
    alL = f32x4{0.f,0.f,0.f,0.f}; alH = f32x4{0.f,0.f,0.f,0.f};
    for (int r = 0; r < 4; r++) { mL[r] = mH[r] = -1e30f; }

    auto stage = [&](int it, unsigned short* Kd, unsigned short* Vd) {
        const int kv0 = it * 64;
        for (int c = tid; c < 512; c += 256) {
            int row = c >> 3, g = c & 7;
            int gc = ((g ^ (row & 7)) << 3);
            gld_lds16(Kg + (size_t)(kv0 + row) * DKK + gc, Kd + c * 8);
            gld_lds16(Vg + (size_t)row * SS + kv0 + gc, Vd + c * 8);
        }
    };

    const float C1 = 0.18033688011112042f;  // log2(e) / sqrt(DK)=8

    auto do_tile = [&](const unsigned short* Kd, const unsigned short* Vd,
                       bf16x8 q0f, bf16x8 q1f, bool diag,
                       f32x4* ao, f32x4& al, float* mr) {
        f32x4 sc[4];
        for (int j = 0; j < 4; j++) {
            const unsigned short* kr = Kd + (j * 16 + l16) * 64;
            bf16x8 kf0 = *reinterpret_cast<const bf16x8*>(kr + ((quad ^ sw) << 3));
            bf16x8 kf1 = *reinterpret_cast<const bf16x8*>(kr + (((4 + quad) ^ sw) << 3));
            f32x4 s = f32x4{0.f, 0.f, 0.f, 0.f};
            s = __builtin_amdgcn_mfma_f32_16x16x32_bf16(q0f, kf0, s, 0, 0, 0);
            s = __builtin_amdgcn_mfma_f32_16x16x32_bf16(q1f, kf1, s, 0, 0, 0);
            sc[j] = s;
        }
        if (diag) {
            for (int j = 0; j < 4; j++) {
                int lcol = j * 16 + l16;
                for (int r = 0; r < 4; r++) {
                    int lrow = wave * 16 + quad * 4 + r;
                    if (lcol > lrow) sc[j][r] = -1e30f;
                }
            }
        }
        float ar[4];
        for (int r = 0; r < 4; r++) {
            float mx = red_max16(fmaxf(fmaxf(sc[0][r], sc[1][r]), fmaxf(sc[2][r], sc[3][r])));
            float mnew = fmaxf(mr[r], mx);
            ar[r] = exp2f((mr[r] - mnew) * C1);
            float nb = -mnew * C1;
            for (int j = 0; j < 4; j++)
                sc[j][r] = exp2f(fmaf(sc[j][r], C1, nb));
            mr[r] = mnew;
        }
        for (int j = 0; j < 4; j++)
            for (int r = 0; r < 4; r++) ao[j][r] *= ar[r];
        for (int r = 0; r < 4; r++) al[r] *= ar[r];

        // P: C-layout -> per-wave LDS (packed cvt) -> A-layout (same-wave RAW, lgkm-ordered)
        unsigned short* Pw = Ps[wave];
        for (int r = 0; r < 4; r++) {
            unsigned pA = pk_bf16(sc[0][r], sc[1][r]);
            unsigned pB = pk_bf16(sc[2][r], sc[3][r]);
            int ro = (quad * 4 + r) * 72;
            Pw[ro + l16]      = (unsigned short)pA;
            Pw[ro + 16 + l16] = (unsigned short)(pA >> 16);
            Pw[ro + 32 + l16] = (unsigned short)pB;
            Pw[ro + 48 + l16] = (unsigned short)(pB >> 16);
        }

        for (int ko = 0; ko < 64; ko += 32) {
            bf16x8 pf = *reinterpret_cast<const bf16x8*>(Pw + l16 * 72 + ko + quad * 8);
            al = __builtin_amdgcn_mfma_f32_16x16x32_bf16(pf, vone, al, 0, 0, 0);
            int gh = (ko >> 3) + quad;
            for (int j = 0; j < 4; j++) {
                bf16x8 vf = *reinterpret_cast<const bf16x8*>(Vd + (j * 16 + l16) * 64 + ((gh ^ sw) << 3));
                ao[j] = __builtin_amdgcn_mfma_f32_16x16x32_bf16(pf, vf, ao[j], 0, 0, 0);
            }
        }
    };

    // ping-pong K-loop: raw barriers + vmcnt(4); next tile's LDS-DMA stays in flight.
    stage(0, K0s, V0s);
    int it = 0;
    while (true) {
        BARRIER();
        if (it + 1 < nIter) { stage(it + 1, K1s, V1s); WAIT_VM4(); } else WAIT_VM0();
        BARRIER();
        do_tile(K0s, V0s, qH0, qH1, it == nIter - 1, aoH, alH, mH);
        if (it <= t) do_tile(K0s, V0s, qL0, qL1, it == t, aoL, alL, mL);
        if (++it >= nIter) break;

        BARRIER();
        if (it + 1 < nIter) { stage(it + 1, K0s, V0s); WAIT_VM4(); } else WAIT_VM0();
        BARRIER();
        do_tile(K1s, V1s, qH0, qH1, it == nIter - 1, aoH, alH, mH);
        if (it <= t) do_tile(K1s, V1s, qL0, qL1, it == t, aoL, alL, mL);
        if (++it >= nIter) break;
    }

    const int b = bh >> 4, h = bh & 15;
    for (int r = 0; r < 4; r++) {
        float invL = __builtin_amdgcn_rcpf(alL[r]);
        float invH = __builtin_amdgcn_rcpf(alH[r]);
        int srL = qlo + wave * 16 + quad * 4 + r;
        int srH = qhi + wave * 16 + quad * 4 + r;
        for (int j = 0; j < 4; j++) {
            attn[((size_t)(b * SS + srL)) * DD + h * DKK + j * 16 + l16] = f2bf(aoL[j][r] * invL);
            attn[((size_t)(b * SS + srH)) * DD + h * DKK + j * 16 + l16] = f2bf(aoH[j][r] * invH);
        }
    }
}

// ---------------- launch ----------------
extern "C" void kernel_launch(void* const* d_in, const int* in_sizes, int n_in,
                              void* d_out, int out_size, void* d_ws, size_t ws_size,
                              hipStream_t stream) {
    const float* x  = (const float*)d_in[0];
    const float* Wq = (const float*)d_in[1];
    const float* Wk = (const float*)d_in[2];
    const float* Wv = (const float*)d_in[3];
    const float* Wo = (const float*)d_in[4];

    char* ws = (char*)d_ws;
    const size_t MB = 1u << 20;
    unsigned short* xb    = (unsigned short*)(ws);             // 8 MB; reused as attnb later
    unsigned short* wb    = (unsigned short*)(ws + 8  * MB);   // 8 MB  [Wq|Wk|Wv|Wo] bf16
    unsigned short* Qbuf  = (unsigned short*)(ws + 16 * MB);   // 8 MB [B,H,S,DK]
    unsigned short* Kbuf  = (unsigned short*)(ws + 24 * MB);   // 8 MB [B,H,S,DK]
    unsigned short* Vtbuf = (unsigned short*)(ws + 32 * MB);   // 8 MB [B,H,DK,S]
    unsigned short* attnb = xb;   // xb is dead after gemm_qkv; alias saves 8 MB

    cast_all<<<8192, 256, 0, stream>>>(x, Wq, Wk, Wv, Wo, xb, wb);

    // fused QKV projection: N=3072 packed, grid 768 blocks = 3/CU
    gemm_qkv<<<dim3(24, 32), 256, 0, stream>>>(xb, wb, Qbuf, Kbuf, Vtbuf);

    // paired-tile flash attention: grid 512 blocks, uniform 33 tile-units each
    attn_kernel<<<dim3(16, BB * HH), 256, 0, stream>>>(Qbuf, Kbuf, Vtbuf, attnb);

    // out-projection: 64x128 tile, grid 512 = 2/CU, fp32 epilogue
    gemm_out<<<dim3(8, 64), 256, 0, stream>>>(attnb, wb + 3 * 1024 * 1024, (float*)d_out);
}